// Round 13
// baseline (164.218 us; speedup 1.0000x reference)
//
#include <hip/hip_runtime.h>

// DeformConv2dBlock on gfx950: B=8, C=64, H=W=128, N=9 taps, pad=1.
// R10: offset conv split into k_off (writes fp16 offsets + per-4row oow flags);
// k_fused = persistent 4-row blocks (grid 256), weights staged in LDS once per
// block, 4-slot ring rolling 3 stages/row (2 forward + 1 stage-back).

typedef _Float16 h2    __attribute__((ext_vector_type(2)));
typedef _Float16 f16x8 __attribute__((ext_vector_type(8)));
typedef float    f32x4 __attribute__((ext_vector_type(4)));

#define MFMAH(a, b, c) __builtin_amdgcn_mfma_f32_16x16x32_f16(a, b, c, 0, 0, 0)

#define RING_SZ 68608            // 4 slots * 134 recs * 128 B
#define LDS_TOT (RING_SZ + 73728)

__device__ __forceinline__ unsigned short f2h(float f) {
    return __builtin_bit_cast(unsigned short, (_Float16)f);
}
__device__ __forceinline__ float h2f_bits(unsigned u) {
    return (float)__builtin_bit_cast(_Float16, (unsigned short)(u & 0xffffu));
}
__device__ __forceinline__ unsigned dup16(float g) {
    _Float16 t = (_Float16)g;
    h2 r = {t, t};
    return __builtin_bit_cast(unsigned, r);
}

__device__ __forceinline__ void blend8(const uint4* clo, const uint4* chi, uint4 gq,
                                       f16x8& bfr0, f16x8& bfr1) {
    h2 g0 = __builtin_bit_cast(h2, gq.x), g1 = __builtin_bit_cast(h2, gq.y);
    h2 g2 = __builtin_bit_cast(h2, gq.z), g3 = __builtin_bit_cast(h2, gq.w);
    const unsigned* c0 = (const unsigned*)&clo[0];
    const unsigned* c1 = (const unsigned*)&clo[1];
    const unsigned* c2 = (const unsigned*)&clo[2];
    const unsigned* c3 = (const unsigned*)&clo[3];
    const unsigned* e0 = (const unsigned*)&chi[0];
    const unsigned* e1 = (const unsigned*)&chi[1];
    const unsigned* e2 = (const unsigned*)&chi[2];
    const unsigned* e3 = (const unsigned*)&chi[3];
    unsigned owl[4], owh[4];
#pragma unroll
    for (int d = 0; d < 4; ++d) {
        h2 sl = __builtin_bit_cast(h2, c0[d]) * g0;
        sl = __builtin_elementwise_fma(__builtin_bit_cast(h2, c1[d]), g1, sl);
        sl = __builtin_elementwise_fma(__builtin_bit_cast(h2, c2[d]), g2, sl);
        sl = __builtin_elementwise_fma(__builtin_bit_cast(h2, c3[d]), g3, sl);
        owl[d] = __builtin_bit_cast(unsigned, sl);
        h2 sh = __builtin_bit_cast(h2, e0[d]) * g0;
        sh = __builtin_elementwise_fma(__builtin_bit_cast(h2, e1[d]), g1, sh);
        sh = __builtin_elementwise_fma(__builtin_bit_cast(h2, e2[d]), g2, sh);
        sh = __builtin_elementwise_fma(__builtin_bit_cast(h2, e3[d]), g3, sh);
        owh[d] = __builtin_bit_cast(unsigned, sh);
    }
    bfr0 = __builtin_bit_cast(f16x8, *(const uint4*)owl);
    bfr1 = __builtin_bit_cast(f16x8, *(const uint4*)owh);
}

// x[b][c][h][w] f32 -> xt[b][h][w][c] fp16
__global__ __launch_bounds__(256) void k_prep_xt(const float* __restrict__ x,
                                                 unsigned short* __restrict__ xt) {
    __shared__ float xs[64][129];
    const int bh = blockIdx.x;
    const int h = bh & 127, b = bh >> 7;
    const float* xr = x + ((size_t)b * 64 * 128 + h) * 128;
    for (int idx = threadIdx.x; idx < 8192; idx += 256) {
        int c = idx >> 7, w = idx & 127;
        xs[c][w] = xr[(size_t)c * 16384 + w];
    }
    __syncthreads();
    unsigned short* xto = xt + ((size_t)bh << 13);
    for (int j = threadIdx.x; j < 1024; j += 256) {
        int w = j >> 3, c0 = (j & 7) << 3;
        unsigned short tmp[8];
#pragma unroll
        for (int e = 0; e < 8; ++e) tmp[e] = f2h(xs[c0 + e][w]);
        *(uint4*)(xto + w * 64 + c0) = *(const uint4*)tmp;
    }
}

// Fragment-ordered fp16 weights (layout as R3..R9) + zero the oow flags.
__global__ void k_prep_w(const float* __restrict__ w_conv, const float* __restrict__ w_off,
                         unsigned short* __restrict__ w_m2, unsigned short* __restrict__ woff2,
                         int* __restrict__ flags) {
    int t = blockIdx.x * 256 + threadIdx.x;
    if (blockIdx.x == 0) flags[threadIdx.x] = 0;   // 256 flags
    if (t < 36864) {
        int r = t & 511;
        int fid = t >> 9;
        int l15 = r >> 5, q4 = (r >> 3) & 3, e = t & 7;
        int chunk = fid & 1, of = (fid >> 1) & 3, n = fid >> 3;
        int o = of * 16 + l15, c = chunk * 32 + q4 * 8 + e;
        w_m2[t] = f2h(w_conv[(o * 64 + c) * 9 + n]);
    }
    int t2 = t - 36864;
    if (t2 >= 0 && t2 < 18432) {
        int r = t2 & 511;
        int fid = t2 >> 9;
        int l15 = r >> 5, q4 = (r >> 3) & 3, e = t2 & 7;
        int kc = fid & 1, half = (fid >> 1) & 1, rj = fid >> 2;
        int k = half * 16 + l15, c = kc * 32 + q4 * 8 + e;
        woff2[t2] = (k < 18) ? f2h(w_off[(k * 64 + c) * 9 + rj]) : (unsigned short)0;
    }
}

// Offset conv: block = (b, h, wt-half): 64 px. Writes offg[pix][24] fp16 and
// sets flags[b*32 + h/4] if any corner row leaves the 4-row tap window.
__global__ __launch_bounds__(256) void k_off(
    const unsigned short* __restrict__ xt, const unsigned short* __restrict__ woff2,
    const float* __restrict__ b_off, _Float16* __restrict__ offg,
    int* __restrict__ flags) {
    __shared__ __align__(16) unsigned char raw3[3 * 66 * 128];

    const int gb = blockIdx.x;
    const int wt = (gb & 1) << 6, h = (gb >> 1) & 127, b = gb >> 8;

    const int tid  = threadIdx.x;
    const int lane = tid & 63, wid = tid >> 6;
    const int l15  = lane & 15, q4 = lane >> 4;
    const int lofs = ((l15 << 2) + q4) << 3;
    const int px   = wid * 16 + l15;

    const unsigned short* xtb = xt + ((size_t)b << 20);

    // stage rows h-1..h+1, cols wt-1..wt+64 (66), zero-filled, swizzled
    for (int idx = tid; idx < 1584; idx += 256) {
        int rec = idx >> 3, cc = idx & 7;
        int rl = rec / 66, col = rec - rl * 66;
        int xr = h - 1 + rl, xc = wt - 1 + col;
        uint4 v = make_uint4(0, 0, 0, 0);
        if (xr >= 0 && xr < 128 && xc >= 0 && xc < 128)
            v = *(const uint4*)(xtb + ((((size_t)xr << 7) + xc) << 6) + (cc << 3));
        *(uint4*)(raw3 + (rec << 7) + ((cc ^ (col & 7)) << 4)) = v;
    }
    __syncthreads();

    f32x4 o0 = {0.f, 0.f, 0.f, 0.f}, o1 = {0.f, 0.f, 0.f, 0.f};
#pragma unroll
    for (int rj = 0; rj < 9; ++rj) {
        const int dr = rj / 3, dj = rj % 3;
        const int colw = px + dj;
        const int recb = dr * 66 + colw;
        const int swz  = colw & 7;
#pragma unroll
        for (int kc = 0; kc < 2; ++kc) {
            f16x8 bfrag = *(const f16x8*)(raw3 + (recb << 7) + ((((kc << 2) + q4) ^ swz) << 4));
            f16x8 a0 = *(const f16x8*)((const _Float16*)woff2 + ((((rj * 2 + 0) << 1) + kc) << 9) + lofs);
            f16x8 a1 = *(const f16x8*)((const _Float16*)woff2 + ((((rj * 2 + 1) << 1) + kc) << 9) + lofs);
            o0 = MFMAH(a0, bfrag, o0);
            o1 = MFMAH(a1, bfrag, o1);
        }
    }

    float4 bo = *(const float4*)(b_off + (q4 << 2));
    float2 bo2 = *(const float2*)(b_off + 16);
    const float bov[4] = {bo.x, bo.y, bo.z, bo.w};
    const size_t pix = ((size_t)(b * 128 + h)) * 128 + wt + px;
    _Float16* og = offg + pix * 24;

    bool oow = false;
#pragma unroll
    for (int rg = 0; rg < 4; ++rg) {
        int o = (q4 << 2) + rg;
        _Float16 v16 = (_Float16)(o0[rg] + bov[rg]);
        og[o] = v16;
        if (o < 9) {   // x-offset channel -> row window check for tap n = o
            int g = o / 3;
            float pxf = (float)(h + g) + (float)v16;
            float fx = floorf(pxf);
            int qx0 = (int)fminf(fmaxf(fx, 0.f), 129.f);
            int qx1 = (int)fminf(fmaxf(fx + 1.f, 0.f), 129.f);
            int t0 = qx0 - h - g + 1, t1 = qx1 - h - g + 1;
            oow |= ((unsigned)t0 > 3u) | ((unsigned)t1 > 3u);
        }
        if (q4 == 0 && rg < 2)
            og[16 + rg] = (_Float16)(o1[rg] + (rg ? bo2.y : bo2.x));
    }
    if (__any(oow) && lane == 0) atomicOr(flags + ((b << 5) | (h >> 2)), 1);
}

// Main: persistent 4-row block (b, h4). 512 thr, 8 waves x 16 px = 128 px/row.
__global__ __launch_bounds__(512, 1) void k_fused(
    const float* __restrict__ x, const unsigned short* __restrict__ xt,
    const unsigned short* __restrict__ w_m2g, const _Float16* __restrict__ offg,
    const int* __restrict__ flags, float* __restrict__ out) {

    extern __shared__ __align__(16) unsigned char lds[];
    unsigned char* raw  = lds;                        // 4-slot row ring (134 recs/row)
    _Float16*      wlds = (_Float16*)(lds + RING_SZ); // w_m2 (36864 halves)

    const int wk = ((blockIdx.x & 7) << 5) | (blockIdx.x >> 3);   // 256 = 8 XCD x 32
    const int b = wk >> 5, h4 = wk & 31, h = h4 << 2;

    const int tid  = threadIdx.x;
    const int lane = tid & 63, wid = tid >> 6;
    const int l15  = lane & 15, q4 = lane >> 4;
    const int lofs = ((l15 << 2) + q4) << 3;
    const int px   = wid * 16 + l15;

    const unsigned short* xtb = xt + ((size_t)b << 20);
    const bool slow = (flags[(b << 5) | h4] != 0);

    // ---- stage initial ring rows (unpadded h-2..h+1) + full weight array ----
    for (int idx = tid; idx < 4288; idx += 512) {
        int rec = idx >> 3, cc = idx & 7;
        int rl = rec / 134, col = rec - rl * 134;
        int xr = h - 2 + rl, xc = col - 3;
        uint4 v = make_uint4(0, 0, 0, 0);
        if (xr >= 0 && xr < 128 && xc >= 0 && xc < 128)
            v = *(const uint4*)(xtb + ((((size_t)xr << 7) + xc) << 6) + (cc << 3));
        *(uint4*)(raw + (((xr + 4) & 3) * 134 + col << 7) + ((cc ^ (col & 7)) << 4)) = v;
    }
    for (int idx = tid; idx < 4608; idx += 512)
        ((uint4*)wlds)[idx] = ((const uint4*)w_m2g)[idx];
    __syncthreads();

    uint4 pf[3];
    int prec[3], pcc[3];
    auto PREF = [&](int u) {   // prefetch unpadded row u into regs
#pragma unroll
        for (int k = 0; k < 3; ++k) {
            int idx = tid + (k << 9);
            bool v = idx < 1072;
            int rec = idx >> 3;
            pcc[k] = idx & 7;
            int xc = rec - 3;
            uint4 vv = make_uint4(0, 0, 0, 0);
            if (v && u >= 0 && u < 128 && xc >= 0 && xc < 128)
                vv = *(const uint4*)(xtb + ((((size_t)u << 7) + xc) << 6) + (pcc[k] << 3));
            prec[k] = v ? rec : -1;
            pf[k] = vv;
        }
    };
    auto WRB = [&](int u) {    // write prefetched row u into its ring slot
        const int slt = (u + 4) & 3;
#pragma unroll
        for (int k = 0; k < 3; ++k)
            if (prec[k] >= 0)
                *(uint4*)(raw + ((slt * 134 + prec[k]) << 7) + ((pcc[k] ^ (prec[k] & 7)) << 4)) = pf[k];
    };

    if (!slow) {
        uint4 cloA[4], chiA[4], cloB[4], chiB[4];
        uint4 gqA, gqB;
        f16x8 waA[8], waB[8];

        for (int r = 0; r < 4; ++r) {
            const int R = h + r;
            const float rbF = (float)R;

            // my pixel's 18 offsets (fp16, 48B aligned)
            const _Float16* obp = offg + ((size_t)((b * 128 + R)) * 128 + px) * 24;
            uint4 oA = *(const uint4*)obp;
            uint4 oB = *(const uint4*)(obp + 8);
            unsigned oC = *(const unsigned*)(obp + 16);
            const unsigned owr[9] = {oA.x, oA.y, oA.z, oA.w, oB.x, oB.y, oB.z, oB.w, oC};
#define OXQ(n) h2f_bits(owr[(n) >> 1] >> (((n) & 1) << 4))
#define OYQ(n) h2f_bits(owr[(9 + (n)) >> 1] >> (((9 + (n)) & 1) << 4))

            // residual prefetch for this row
            const size_t obase = ((size_t)b << 20) + (size_t)R * 128 + px;
            float xres[4][4];
#pragma unroll
            for (int of = 0; of < 4; ++of)
#pragma unroll
                for (int rg = 0; rg < 4; ++rg)
                    xres[of][rg] = x[obase + (size_t)((of << 4) + (q4 << 2) + rg) * 16384];

            f32x4 acc[4];
#pragma unroll
            for (int of = 0; of < 4; ++of) acc[of] = (f32x4){0.f, 0.f, 0.f, 0.f};

#define TAPLOAD(n, S)                                                                    \
            {                                                                            \
                constexpr int g = (n) / 3, dj = (n) % 3;                                 \
                float ox = OXQ(n), oy = OYQ(n);                                          \
                float pxf = rbF + (float)g + ox, pyf = (float)(px + dj) + oy;            \
                float fx = floorf(pxf), fy = floorf(pyf);                                \
                float qx0f = fminf(fmaxf(fx, 0.f), 129.f);                               \
                float qx1f = fminf(fmaxf(fx + 1.f, 0.f), 129.f);                         \
                float qy0f = fminf(fmaxf(fy, 0.f), 129.f);                               \
                float qy1f = fminf(fmaxf(fy + 1.f, 0.f), 129.f);                         \
                float pxc = fminf(fmaxf(pxf, 0.f), 129.f);                               \
                float pyc = fminf(fmaxf(pyf, 0.f), 129.f);                               \
                float ax0 = 1.f + (qx0f - pxc), ax1 = 1.f - (qx1f - pxc);                \
                float ay0 = 1.f + (qy0f - pyc), ay1 = 1.f - (qy1f - pyc);                \
                int r0 = (((int)qx0f + 3) & 3) * 134, r1 = (((int)qx1f + 3) & 3) * 134;  \
                int c0 = (int)qy0f + 2, c1 = (int)qy1f + 2;                              \
                int blt = (r0 + c0) << 7, brb = (r1 + c1) << 7;                          \
                int blb = (r0 + c1) << 7, brt = (r1 + c0) << 7;                          \
                int z0 = ((q4 ^ c0) & 7) << 4, z1 = ((q4 ^ c1) & 7) << 4;                \
                clo##S[0] = *(const uint4*)(raw + blt + z0);                             \
                chi##S[0] = *(const uint4*)(raw + blt + (z0 ^ 64));                      \
                clo##S[1] = *(const uint4*)(raw + brb + z1);                             \
                chi##S[1] = *(const uint4*)(raw + brb + (z1 ^ 64));                      \
                clo##S[2] = *(const uint4*)(raw + blb + z1);                             \
                chi##S[2] = *(const uint4*)(raw + blb + (z1 ^ 64));                      \
                clo##S[3] = *(const uint4*)(raw + brt + z0);                             \
                chi##S[3] = *(const uint4*)(raw + brt + (z0 ^ 64));                      \
                gq##S = make_uint4(dup16(ax0 * ay0), dup16(ax1 * ay1),                   \
                                   dup16(ax0 * ay1), dup16(ax1 * ay0));                  \
                _Pragma("unroll")                                                        \
                for (int of = 0; of < 4; ++of) {                                         \
                    wa##S[2 * of]     = *(const f16x8*)(wlds + (((n) * 8 + of * 2 + 0) << 9) + lofs); \
                    wa##S[2 * of + 1] = *(const f16x8*)(wlds + (((n) * 8 + of * 2 + 1) << 9) + lofs); \
                }                                                                        \
            }
#define TAPEXEC(S)                                                                       \
            {                                                                            \
                f16x8 bfr0, bfr1;                                                        \
                blend8(clo##S, chi##S, gq##S, bfr0, bfr1);                               \
                _Pragma("unroll")                                                        \
                for (int of = 0; of < 4; ++of) {                                         \
                    acc[of] = MFMAH(wa##S[2 * of],     bfr0, acc[of]);                   \
                    acc[of] = MFMAH(wa##S[2 * of + 1], bfr1, acc[of]);                   \
                }                                                                        \
            }

            // group 0 (window padded [R-1, R+2]); prefetch padded R+3 = unpadded R+2
            PREF(R + 2);
            TAPLOAD(0, A)
            TAPLOAD(1, B) TAPEXEC(A)
            TAPLOAD(2, A) TAPEXEC(B)
                          TAPEXEC(A)
            __syncthreads(); WRB(R + 2); __syncthreads();

            // group 1 (window [R, R+3]); prefetch padded R+4 = unpadded R+3
            PREF(R + 3);
            TAPLOAD(3, A)
            TAPLOAD(4, B) TAPEXEC(A)
            TAPLOAD(5, A) TAPEXEC(B)
                          TAPEXEC(A)
            __syncthreads(); WRB(R + 3); __syncthreads();

            // group 2 (window [R+1, R+4]); prefetch stage-back padded R = unpadded R-1
            if (r < 3) PREF(R - 1);
            TAPLOAD(6, A)
            TAPLOAD(7, B) TAPEXEC(A)
            TAPLOAD(8, A) TAPEXEC(B)
                          TAPEXEC(A)
#undef TAPLOAD
#undef TAPEXEC
#undef OXQ
#undef OYQ

            // epilogue row R
#pragma unroll
            for (int of = 0; of < 4; ++of)
#pragma unroll
                for (int rg = 0; rg < 4; ++rg)
                    out[obase + (size_t)((of << 4) + (q4 << 2) + rg) * 16384] = acc[of][rg] + xres[of][rg];

            if (r < 3) { __syncthreads(); WRB(R - 1); __syncthreads(); }
        }
    } else {
        // ---- SLOW PATH (rare): all-global gather for 4 rows ----
        for (int r = 0; r < 4; ++r) {
            const int R = h + r;
            const _Float16* obp = offg + ((size_t)((b * 128 + R)) * 128 + px) * 24;
            const size_t obase = ((size_t)b << 20) + (size_t)R * 128 + px;
            f32x4 acc[4];
#pragma unroll
            for (int of = 0; of < 4; ++of) acc[of] = (f32x4){0.f, 0.f, 0.f, 0.f};
            for (int n = 0; n < 9; ++n) {
                const int g = n / 3, dj = n % 3;
                float ox = (float)obp[n], oy = (float)obp[9 + n];
                float pxf = (float)(R + g) + ox, pyf = (float)(px + dj) + oy;
                float fx = floorf(pxf), fy = floorf(pyf);
                float qx0f = fminf(fmaxf(fx, 0.f), 129.f);
                float qx1f = fminf(fmaxf(fx + 1.f, 0.f), 129.f);
                float qy0f = fminf(fmaxf(fy, 0.f), 129.f);
                float qy1f = fminf(fmaxf(fy + 1.f, 0.f), 129.f);
                float pxc = fminf(fmaxf(pxf, 0.f), 129.f);
                float pyc = fminf(fmaxf(pyf, 0.f), 129.f);
                float ax0 = 1.f + (qx0f - pxc), ax1 = 1.f - (qx1f - pxc);
                float ay0 = 1.f + (qy0f - pyc), ay1 = 1.f - (qy1f - pyc);
                int qx[2] = {(int)qx0f, (int)qx1f};
                int qy[2] = {(int)qy0f, (int)qy1f};
                uint4 clo[4], chi[4];
                const int rsel[4] = {0, 1, 0, 1}, csel[4] = {0, 1, 1, 0};
#pragma unroll
                for (int j = 0; j < 4; ++j) {
                    int rx = qx[rsel[j]], ry = qy[csel[j]];
                    bool v = (rx >= 1) & (rx <= 128) & (ry >= 1) & (ry <= 128);
                    clo[j] = make_uint4(0, 0, 0, 0);
                    chi[j] = make_uint4(0, 0, 0, 0);
                    if (v) {
                        const unsigned short* gp = xtb + ((((size_t)(rx - 1) << 7) + (ry - 1)) << 6);
                        clo[j] = *(const uint4*)(gp + (q4 << 3));
                        chi[j] = *(const uint4*)(gp + (q4 << 3) + 32);
                    }
                }
                uint4 gq = make_uint4(dup16(ax0 * ay0), dup16(ax1 * ay1),
                                      dup16(ax0 * ay1), dup16(ax1 * ay0));
                f16x8 bfr0, bfr1;
                blend8(clo, chi, gq, bfr0, bfr1);
#pragma unroll
                for (int of = 0; of < 4; ++of) {
                    f16x8 a0 = *(const f16x8*)(wlds + ((n * 8 + of * 2 + 0) << 9) + lofs);
                    f16x8 a1 = *(const f16x8*)(wlds + ((n * 8 + of * 2 + 1) << 9) + lofs);
                    acc[of] = MFMAH(a0, bfr0, acc[of]);
                    acc[of] = MFMAH(a1, bfr1, acc[of]);
                }
            }
#pragma unroll
            for (int of = 0; of < 4; ++of)
#pragma unroll
                for (int rg = 0; rg < 4; ++rg) {
                    size_t a = obase + (size_t)((of << 4) + (q4 << 2) + rg) * 16384;
                    out[a] = acc[of][rg] + x[a];
                }
        }
    }
}

extern "C" void kernel_launch(void* const* d_in, const int* in_sizes, int n_in,
                              void* d_out, int out_size, void* d_ws, size_t ws_size,
                              hipStream_t stream) {
    const float* x      = (const float*)d_in[0];
    const float* w_off  = (const float*)d_in[1];
    const float* b_off  = (const float*)d_in[2];
    const float* w_conv = (const float*)d_in[3];

    // ws layout (halves): xt 8388608 | w_m2 36864 | woff2 18432 | offg 3145728 | flags 256 ints
    unsigned short* xt    = (unsigned short*)d_ws;
    unsigned short* w_m2  = xt + (size_t)8 * 128 * 128 * 64;
    unsigned short* woff2 = w_m2 + 36864;
    _Float16*       offg  = (_Float16*)(woff2 + 18432);
    int*            flags = (int*)(offg + (size_t)131072 * 24);

    hipFuncSetAttribute((const void*)k_fused,
                        hipFuncAttributeMaxDynamicSharedMemorySize, LDS_TOT);

    hipLaunchKernelGGL(k_prep_xt, dim3(1024), dim3(256), 0, stream, x, xt);
    hipLaunchKernelGGL(k_prep_w,  dim3(216),  dim3(256), 0, stream, w_conv, w_off, w_m2, woff2, flags);
    hipLaunchKernelGGL(k_off,     dim3(2048), dim3(256), 0, stream,
                       xt, woff2, b_off, offg, flags);
    hipLaunchKernelGGL(k_fused,   dim3(256),  dim3(512), LDS_TOT, stream,
                       x, xt, w_m2, offg, flags, (float*)d_out);
}

// Round 14
// 163.792 us; speedup vs baseline: 1.0026x; 1.0026x over previous
//
#include <hip/hip_runtime.h>

// DeformConv2dBlock on gfx950: B=8, C=64, H=W=128, N=9 taps, pad=1.
// R10: offset conv split into k_off (writes fp16 offsets + per-4row oow flags);
// k_fused = persistent 4-row blocks (grid 256), weights staged in LDS once per
// block, 4-slot ring rolling 3 stages/row (2 forward + 1 stage-back).

typedef _Float16 h2    __attribute__((ext_vector_type(2)));
typedef _Float16 f16x8 __attribute__((ext_vector_type(8)));
typedef float    f32x4 __attribute__((ext_vector_type(4)));

#define MFMAH(a, b, c) __builtin_amdgcn_mfma_f32_16x16x32_f16(a, b, c, 0, 0, 0)

#define RING_SZ 68608            // 4 slots * 134 recs * 128 B
#define LDS_TOT (RING_SZ + 73728)

__device__ __forceinline__ unsigned short f2h(float f) {
    return __builtin_bit_cast(unsigned short, (_Float16)f);
}
__device__ __forceinline__ float h2f_bits(unsigned u) {
    return (float)__builtin_bit_cast(_Float16, (unsigned short)(u & 0xffffu));
}
__device__ __forceinline__ unsigned dup16(float g) {
    _Float16 t = (_Float16)g;
    h2 r = {t, t};
    return __builtin_bit_cast(unsigned, r);
}

__device__ __forceinline__ void blend8(const uint4* clo, const uint4* chi, uint4 gq,
                                       f16x8& bfr0, f16x8& bfr1) {
    h2 g0 = __builtin_bit_cast(h2, gq.x), g1 = __builtin_bit_cast(h2, gq.y);
    h2 g2 = __builtin_bit_cast(h2, gq.z), g3 = __builtin_bit_cast(h2, gq.w);
    const unsigned* c0 = (const unsigned*)&clo[0];
    const unsigned* c1 = (const unsigned*)&clo[1];
    const unsigned* c2 = (const unsigned*)&clo[2];
    const unsigned* c3 = (const unsigned*)&clo[3];
    const unsigned* e0 = (const unsigned*)&chi[0];
    const unsigned* e1 = (const unsigned*)&chi[1];
    const unsigned* e2 = (const unsigned*)&chi[2];
    const unsigned* e3 = (const unsigned*)&chi[3];
    unsigned owl[4], owh[4];
#pragma unroll
    for (int d = 0; d < 4; ++d) {
        h2 sl = __builtin_bit_cast(h2, c0[d]) * g0;
        sl = __builtin_elementwise_fma(__builtin_bit_cast(h2, c1[d]), g1, sl);
        sl = __builtin_elementwise_fma(__builtin_bit_cast(h2, c2[d]), g2, sl);
        sl = __builtin_elementwise_fma(__builtin_bit_cast(h2, c3[d]), g3, sl);
        owl[d] = __builtin_bit_cast(unsigned, sl);
        h2 sh = __builtin_bit_cast(h2, e0[d]) * g0;
        sh = __builtin_elementwise_fma(__builtin_bit_cast(h2, e1[d]), g1, sh);
        sh = __builtin_elementwise_fma(__builtin_bit_cast(h2, e2[d]), g2, sh);
        sh = __builtin_elementwise_fma(__builtin_bit_cast(h2, e3[d]), g3, sh);
        owh[d] = __builtin_bit_cast(unsigned, sh);
    }
    bfr0 = __builtin_bit_cast(f16x8, *(const uint4*)owl);
    bfr1 = __builtin_bit_cast(f16x8, *(const uint4*)owh);
}

// x[b][c][h][w] f32 -> xt[b][h][w][c] fp16
__global__ __launch_bounds__(256) void k_prep_xt(const float* __restrict__ x,
                                                 unsigned short* __restrict__ xt) {
    __shared__ float xs[64][129];
    const int bh = blockIdx.x;
    const int h = bh & 127, b = bh >> 7;
    const float* xr = x + ((size_t)b * 64 * 128 + h) * 128;
    for (int idx = threadIdx.x; idx < 8192; idx += 256) {
        int c = idx >> 7, w = idx & 127;
        xs[c][w] = xr[(size_t)c * 16384 + w];
    }
    __syncthreads();
    unsigned short* xto = xt + ((size_t)bh << 13);
    for (int j = threadIdx.x; j < 1024; j += 256) {
        int w = j >> 3, c0 = (j & 7) << 3;
        unsigned short tmp[8];
#pragma unroll
        for (int e = 0; e < 8; ++e) tmp[e] = f2h(xs[c0 + e][w]);
        *(uint4*)(xto + w * 64 + c0) = *(const uint4*)tmp;
    }
}

// Fragment-ordered fp16 weights (layout as R3..R9) + zero the oow flags.
__global__ void k_prep_w(const float* __restrict__ w_conv, const float* __restrict__ w_off,
                         unsigned short* __restrict__ w_m2, unsigned short* __restrict__ woff2,
                         int* __restrict__ flags) {
    int t = blockIdx.x * 256 + threadIdx.x;
    if (blockIdx.x == 0) flags[threadIdx.x] = 0;   // 256 flags
    if (t < 36864) {
        int r = t & 511;
        int fid = t >> 9;
        int l15 = r >> 5, q4 = (r >> 3) & 3, e = t & 7;
        int chunk = fid & 1, of = (fid >> 1) & 3, n = fid >> 3;
        int o = of * 16 + l15, c = chunk * 32 + q4 * 8 + e;
        w_m2[t] = f2h(w_conv[(o * 64 + c) * 9 + n]);
    }
    int t2 = t - 36864;
    if (t2 >= 0 && t2 < 18432) {
        int r = t2 & 511;
        int fid = t2 >> 9;
        int l15 = r >> 5, q4 = (r >> 3) & 3, e = t2 & 7;
        int kc = fid & 1, half = (fid >> 1) & 1, rj = fid >> 2;
        int k = half * 16 + l15, c = kc * 32 + q4 * 8 + e;
        woff2[t2] = (k < 18) ? f2h(w_off[(k * 64 + c) * 9 + rj]) : (unsigned short)0;
    }
}

// Offset conv: block = (b, h, wt-half): 64 px. Writes offg[pix][24] fp16 and
// sets flags[b*32 + h/4] if any corner row leaves the 4-row tap window.
__global__ __launch_bounds__(256) void k_off(
    const unsigned short* __restrict__ xt, const unsigned short* __restrict__ woff2,
    const float* __restrict__ b_off, _Float16* __restrict__ offg,
    int* __restrict__ flags) {
    __shared__ __align__(16) unsigned char raw3[3 * 66 * 128];

    const int gb = blockIdx.x;
    const int wt = (gb & 1) << 6, h = (gb >> 1) & 127, b = gb >> 8;

    const int tid  = threadIdx.x;
    const int lane = tid & 63, wid = tid >> 6;
    const int l15  = lane & 15, q4 = lane >> 4;
    const int lofs = ((l15 << 2) + q4) << 3;
    const int px   = wid * 16 + l15;

    const unsigned short* xtb = xt + ((size_t)b << 20);

    // stage rows h-1..h+1, cols wt-1..wt+64 (66), zero-filled, swizzled
    for (int idx = tid; idx < 1584; idx += 256) {
        int rec = idx >> 3, cc = idx & 7;
        int rl = rec / 66, col = rec - rl * 66;
        int xr = h - 1 + rl, xc = wt - 1 + col;
        uint4 v = make_uint4(0, 0, 0, 0);
        if (xr >= 0 && xr < 128 && xc >= 0 && xc < 128)
            v = *(const uint4*)(xtb + ((((size_t)xr << 7) + xc) << 6) + (cc << 3));
        *(uint4*)(raw3 + (rec << 7) + ((cc ^ (col & 7)) << 4)) = v;
    }
    __syncthreads();

    f32x4 o0 = {0.f, 0.f, 0.f, 0.f}, o1 = {0.f, 0.f, 0.f, 0.f};
#pragma unroll
    for (int rj = 0; rj < 9; ++rj) {
        const int dr = rj / 3, dj = rj % 3;
        const int colw = px + dj;
        const int recb = dr * 66 + colw;
        const int swz  = colw & 7;
#pragma unroll
        for (int kc = 0; kc < 2; ++kc) {
            f16x8 bfrag = *(const f16x8*)(raw3 + (recb << 7) + ((((kc << 2) + q4) ^ swz) << 4));
            f16x8 a0 = *(const f16x8*)((const _Float16*)woff2 + ((((rj * 2 + 0) << 1) + kc) << 9) + lofs);
            f16x8 a1 = *(const f16x8*)((const _Float16*)woff2 + ((((rj * 2 + 1) << 1) + kc) << 9) + lofs);
            o0 = MFMAH(a0, bfrag, o0);
            o1 = MFMAH(a1, bfrag, o1);
        }
    }

    float4 bo = *(const float4*)(b_off + (q4 << 2));
    float2 bo2 = *(const float2*)(b_off + 16);
    const float bov[4] = {bo.x, bo.y, bo.z, bo.w};
    const size_t pix = ((size_t)(b * 128 + h)) * 128 + wt + px;
    _Float16* og = offg + pix * 24;

    bool oow = false;
#pragma unroll
    for (int rg = 0; rg < 4; ++rg) {
        int o = (q4 << 2) + rg;
        _Float16 v16 = (_Float16)(o0[rg] + bov[rg]);
        og[o] = v16;
        if (o < 9) {   // x-offset channel -> row window check for tap n = o
            int g = o / 3;
            float pxf = (float)(h + g) + (float)v16;
            float fx = floorf(pxf);
            int qx0 = (int)fminf(fmaxf(fx, 0.f), 129.f);
            int qx1 = (int)fminf(fmaxf(fx + 1.f, 0.f), 129.f);
            int t0 = qx0 - h - g + 1, t1 = qx1 - h - g + 1;
            oow |= ((unsigned)t0 > 3u) | ((unsigned)t1 > 3u);
        }
        if (q4 == 0 && rg < 2)
            og[16 + rg] = (_Float16)(o1[rg] + (rg ? bo2.y : bo2.x));
    }
    if (__any(oow) && lane == 0) atomicOr(flags + ((b << 5) | (h >> 2)), 1);
}

// Main: persistent 4-row block (b, h4). 512 thr, 8 waves x 16 px = 128 px/row.
__global__ __launch_bounds__(512, 1) void k_fused(
    const float* __restrict__ x, const unsigned short* __restrict__ xt,
    const unsigned short* __restrict__ w_m2g, const _Float16* __restrict__ offg,
    const int* __restrict__ flags, float* __restrict__ out) {

    extern __shared__ __align__(16) unsigned char lds[];
    unsigned char* raw  = lds;                        // 4-slot row ring (134 recs/row)
    _Float16*      wlds = (_Float16*)(lds + RING_SZ); // w_m2 (36864 halves)

    const int wk = ((blockIdx.x & 7) << 5) | (blockIdx.x >> 3);   // 256 = 8 XCD x 32
    const int b = wk >> 5, h4 = wk & 31, h = h4 << 2;

    const int tid  = threadIdx.x;
    const int lane = tid & 63, wid = tid >> 6;
    const int l15  = lane & 15, q4 = lane >> 4;
    const int lofs = ((l15 << 2) + q4) << 3;
    const int px   = wid * 16 + l15;

    const unsigned short* xtb = xt + ((size_t)b << 20);
    const bool slow = (flags[(b << 5) | h4] != 0);

    // ---- stage initial ring rows (unpadded h-2..h+1) + full weight array ----
    for (int idx = tid; idx < 4288; idx += 512) {
        int rec = idx >> 3, cc = idx & 7;
        int rl = rec / 134, col = rec - rl * 134;
        int xr = h - 2 + rl, xc = col - 3;
        uint4 v = make_uint4(0, 0, 0, 0);
        if (xr >= 0 && xr < 128 && xc >= 0 && xc < 128)
            v = *(const uint4*)(xtb + ((((size_t)xr << 7) + xc) << 6) + (cc << 3));
        *(uint4*)(raw + (((xr + 4) & 3) * 134 + col << 7) + ((cc ^ (col & 7)) << 4)) = v;
    }
    for (int idx = tid; idx < 4608; idx += 512)
        ((uint4*)wlds)[idx] = ((const uint4*)w_m2g)[idx];
    __syncthreads();

    uint4 pf[3];
    int prec[3], pcc[3];
    auto PREF = [&](int u) {   // prefetch unpadded row u into regs
#pragma unroll
        for (int k = 0; k < 3; ++k) {
            int idx = tid + (k << 9);
            bool v = idx < 1072;
            int rec = idx >> 3;
            pcc[k] = idx & 7;
            int xc = rec - 3;
            uint4 vv = make_uint4(0, 0, 0, 0);
            if (v && u >= 0 && u < 128 && xc >= 0 && xc < 128)
                vv = *(const uint4*)(xtb + ((((size_t)u << 7) + xc) << 6) + (pcc[k] << 3));
            prec[k] = v ? rec : -1;
            pf[k] = vv;
        }
    };
    auto WRB = [&](int u) {    // write prefetched row u into its ring slot
        const int slt = (u + 4) & 3;
#pragma unroll
        for (int k = 0; k < 3; ++k)
            if (prec[k] >= 0)
                *(uint4*)(raw + ((slt * 134 + prec[k]) << 7) + ((pcc[k] ^ (prec[k] & 7)) << 4)) = pf[k];
    };

    if (!slow) {
        uint4 cloA[4], chiA[4], cloB[4], chiB[4];
        uint4 gqA, gqB;
        f16x8 waA[8], waB[8];

        for (int r = 0; r < 4; ++r) {
            const int R = h + r;
            const float rbF = (float)R;

            // my pixel's 18 offsets (fp16, 48B aligned)
            const _Float16* obp = offg + ((size_t)((b * 128 + R)) * 128 + px) * 24;
            uint4 oA = *(const uint4*)obp;
            uint4 oB = *(const uint4*)(obp + 8);
            unsigned oC = *(const unsigned*)(obp + 16);
            const unsigned owr[9] = {oA.x, oA.y, oA.z, oA.w, oB.x, oB.y, oB.z, oB.w, oC};
#define OXQ(n) h2f_bits(owr[(n) >> 1] >> (((n) & 1) << 4))
#define OYQ(n) h2f_bits(owr[(9 + (n)) >> 1] >> (((9 + (n)) & 1) << 4))

            // residual prefetch for this row
            const size_t obase = ((size_t)b << 20) + (size_t)R * 128 + px;
            float xres[4][4];
#pragma unroll
            for (int of = 0; of < 4; ++of)
#pragma unroll
                for (int rg = 0; rg < 4; ++rg)
                    xres[of][rg] = x[obase + (size_t)((of << 4) + (q4 << 2) + rg) * 16384];

            f32x4 acc[4];
#pragma unroll
            for (int of = 0; of < 4; ++of) acc[of] = (f32x4){0.f, 0.f, 0.f, 0.f};

#define TAPLOAD(n, S)                                                                    \
            {                                                                            \
                constexpr int g = (n) / 3, dj = (n) % 3;                                 \
                float ox = OXQ(n), oy = OYQ(n);                                          \
                float pxf = rbF + (float)g + ox, pyf = (float)(px + dj) + oy;            \
                float fx = floorf(pxf), fy = floorf(pyf);                                \
                float qx0f = fminf(fmaxf(fx, 0.f), 129.f);                               \
                float qx1f = fminf(fmaxf(fx + 1.f, 0.f), 129.f);                         \
                float qy0f = fminf(fmaxf(fy, 0.f), 129.f);                               \
                float qy1f = fminf(fmaxf(fy + 1.f, 0.f), 129.f);                         \
                float pxc = fminf(fmaxf(pxf, 0.f), 129.f);                               \
                float pyc = fminf(fmaxf(pyf, 0.f), 129.f);                               \
                float ax0 = 1.f + (qx0f - pxc), ax1 = 1.f - (qx1f - pxc);                \
                float ay0 = 1.f + (qy0f - pyc), ay1 = 1.f - (qy1f - pyc);                \
                int r0 = (((int)qx0f + 3) & 3) * 134, r1 = (((int)qx1f + 3) & 3) * 134;  \
                int c0 = (int)qy0f + 2, c1 = (int)qy1f + 2;                              \
                int blt = (r0 + c0) << 7, brb = (r1 + c1) << 7;                          \
                int blb = (r0 + c1) << 7, brt = (r1 + c0) << 7;                          \
                int z0 = ((q4 ^ c0) & 7) << 4, z1 = ((q4 ^ c1) & 7) << 4;                \
                clo##S[0] = *(const uint4*)(raw + blt + z0);                             \
                chi##S[0] = *(const uint4*)(raw + blt + (z0 ^ 64));                      \
                clo##S[1] = *(const uint4*)(raw + brb + z1);                             \
                chi##S[1] = *(const uint4*)(raw + brb + (z1 ^ 64));                      \
                clo##S[2] = *(const uint4*)(raw + blb + z1);                             \
                chi##S[2] = *(const uint4*)(raw + blb + (z1 ^ 64));                      \
                clo##S[3] = *(const uint4*)(raw + brt + z0);                             \
                chi##S[3] = *(const uint4*)(raw + brt + (z0 ^ 64));                      \
                gq##S = make_uint4(dup16(ax0 * ay0), dup16(ax1 * ay1),                   \
                                   dup16(ax0 * ay1), dup16(ax1 * ay0));                  \
                _Pragma("unroll")                                                        \
                for (int of = 0; of < 4; ++of) {                                         \
                    wa##S[2 * of]     = *(const f16x8*)(wlds + (((n) * 8 + of * 2 + 0) << 9) + lofs); \
                    wa##S[2 * of + 1] = *(const f16x8*)(wlds + (((n) * 8 + of * 2 + 1) << 9) + lofs); \
                }                                                                        \
            }
#define TAPEXEC(S)                                                                       \
            {                                                                            \
                f16x8 bfr0, bfr1;                                                        \
                blend8(clo##S, chi##S, gq##S, bfr0, bfr1);                               \
                _Pragma("unroll")                                                        \
                for (int of = 0; of < 4; ++of) {                                         \
                    acc[of] = MFMAH(wa##S[2 * of],     bfr0, acc[of]);                   \
                    acc[of] = MFMAH(wa##S[2 * of + 1], bfr1, acc[of]);                   \
                }                                                                        \
            }

            // group 0 (window padded [R-1, R+2]); prefetch padded R+3 = unpadded R+2
            PREF(R + 2);
            TAPLOAD(0, A)
            TAPLOAD(1, B) TAPEXEC(A)
            TAPLOAD(2, A) TAPEXEC(B)
                          TAPEXEC(A)
            __syncthreads(); WRB(R + 2); __syncthreads();

            // group 1 (window [R, R+3]); prefetch padded R+4 = unpadded R+3
            PREF(R + 3);
            TAPLOAD(3, A)
            TAPLOAD(4, B) TAPEXEC(A)
            TAPLOAD(5, A) TAPEXEC(B)
                          TAPEXEC(A)
            __syncthreads(); WRB(R + 3); __syncthreads();

            // group 2 (window [R+1, R+4]); prefetch stage-back padded R = unpadded R-1
            if (r < 3) PREF(R - 1);
            TAPLOAD(6, A)
            TAPLOAD(7, B) TAPEXEC(A)
            TAPLOAD(8, A) TAPEXEC(B)
                          TAPEXEC(A)
#undef TAPLOAD
#undef TAPEXEC
#undef OXQ
#undef OYQ

            // epilogue row R
#pragma unroll
            for (int of = 0; of < 4; ++of)
#pragma unroll
                for (int rg = 0; rg < 4; ++rg)
                    out[obase + (size_t)((of << 4) + (q4 << 2) + rg) * 16384] = acc[of][rg] + xres[of][rg];

            if (r < 3) { __syncthreads(); WRB(R - 1); __syncthreads(); }
        }
    } else {
        // ---- SLOW PATH (rare): all-global gather for 4 rows ----
        for (int r = 0; r < 4; ++r) {
            const int R = h + r;
            const _Float16* obp = offg + ((size_t)((b * 128 + R)) * 128 + px) * 24;
            const size_t obase = ((size_t)b << 20) + (size_t)R * 128 + px;
            f32x4 acc[4];
#pragma unroll
            for (int of = 0; of < 4; ++of) acc[of] = (f32x4){0.f, 0.f, 0.f, 0.f};
            for (int n = 0; n < 9; ++n) {
                const int g = n / 3, dj = n % 3;
                float ox = (float)obp[n], oy = (float)obp[9 + n];
                float pxf = (float)(R + g) + ox, pyf = (float)(px + dj) + oy;
                float fx = floorf(pxf), fy = floorf(pyf);
                float qx0f = fminf(fmaxf(fx, 0.f), 129.f);
                float qx1f = fminf(fmaxf(fx + 1.f, 0.f), 129.f);
                float qy0f = fminf(fmaxf(fy, 0.f), 129.f);
                float qy1f = fminf(fmaxf(fy + 1.f, 0.f), 129.f);
                float pxc = fminf(fmaxf(pxf, 0.f), 129.f);
                float pyc = fminf(fmaxf(pyf, 0.f), 129.f);
                float ax0 = 1.f + (qx0f - pxc), ax1 = 1.f - (qx1f - pxc);
                float ay0 = 1.f + (qy0f - pyc), ay1 = 1.f - (qy1f - pyc);
                int qx[2] = {(int)qx0f, (int)qx1f};
                int qy[2] = {(int)qy0f, (int)qy1f};
                uint4 clo[4], chi[4];
                const int rsel[4] = {0, 1, 0, 1}, csel[4] = {0, 1, 1, 0};
#pragma unroll
                for (int j = 0; j < 4; ++j) {
                    int rx = qx[rsel[j]], ry = qy[csel[j]];
                    bool v = (rx >= 1) & (rx <= 128) & (ry >= 1) & (ry <= 128);
                    clo[j] = make_uint4(0, 0, 0, 0);
                    chi[j] = make_uint4(0, 0, 0, 0);
                    if (v) {
                        const unsigned short* gp = xtb + ((((size_t)(rx - 1) << 7) + (ry - 1)) << 6);
                        clo[j] = *(const uint4*)(gp + (q4 << 3));
                        chi[j] = *(const uint4*)(gp + (q4 << 3) + 32);
                    }
                }
                uint4 gq = make_uint4(dup16(ax0 * ay0), dup16(ax1 * ay1),
                                      dup16(ax0 * ay1), dup16(ax1 * ay0));
                f16x8 bfr0, bfr1;
                blend8(clo, chi, gq, bfr0, bfr1);
#pragma unroll
                for (int of = 0; of < 4; ++of) {
                    f16x8 a0 = *(const f16x8*)(wlds + ((n * 8 + of * 2 + 0) << 9) + lofs);
                    f16x8 a1 = *(const f16x8*)(wlds + ((n * 8 + of * 2 + 1) << 9) + lofs);
                    acc[of] = MFMAH(a0, bfr0, acc[of]);
                    acc[of] = MFMAH(a1, bfr1, acc[of]);
                }
            }
#pragma unroll
            for (int of = 0; of < 4; ++of)
#pragma unroll
                for (int rg = 0; rg < 4; ++rg) {
                    size_t a = obase + (size_t)((of << 4) + (q4 << 2) + rg) * 16384;
                    out[a] = acc[of][rg] + x[a];
                }
        }
    }
}

extern "C" void kernel_launch(void* const* d_in, const int* in_sizes, int n_in,
                              void* d_out, int out_size, void* d_ws, size_t ws_size,
                              hipStream_t stream) {
    const float* x      = (const float*)d_in[0];
    const float* w_off  = (const float*)d_in[1];
    const float* b_off  = (const float*)d_in[2];
    const float* w_conv = (const float*)d_in[3];

    // ws layout (halves): xt 8388608 | w_m2 36864 | woff2 18432 | offg 3145728 | flags 256 ints
    unsigned short* xt    = (unsigned short*)d_ws;
    unsigned short* w_m2  = xt + (size_t)8 * 128 * 128 * 64;
    unsigned short* woff2 = w_m2 + 36864;
    _Float16*       offg  = (_Float16*)(woff2 + 18432);
    int*            flags = (int*)(offg + (size_t)131072 * 24);

    hipFuncSetAttribute((const void*)k_fused,
                        hipFuncAttributeMaxDynamicSharedMemorySize, LDS_TOT);

    hipLaunchKernelGGL(k_prep_xt, dim3(1024), dim3(256), 0, stream, x, xt);
    hipLaunchKernelGGL(k_prep_w,  dim3(216),  dim3(256), 0, stream, w_conv, w_off, w_m2, woff2, flags);
    hipLaunchKernelGGL(k_off,     dim3(2048), dim3(256), 0, stream,
                       xt, woff2, b_off, offg, flags);
    hipLaunchKernelGGL(k_fused,   dim3(256),  dim3(512), LDS_TOT, stream,
                       x, xt, w_m2, offg, flags, (float*)d_out);
}

// Round 15
// 163.539 us; speedup vs baseline: 1.0042x; 1.0015x over previous
//
#include <hip/hip_runtime.h>

// DeformConv2dBlock on gfx950: B=8, C=64, H=W=128, N=9 taps, pad=1.
// R10: offset conv split into k_off (writes fp16 offsets + per-4row oow flags);
// k_fused = persistent 4-row blocks (grid 256), weights staged in LDS once per
// block, 4-slot ring rolling 3 stages/row (2 forward + 1 stage-back).

typedef _Float16 h2    __attribute__((ext_vector_type(2)));
typedef _Float16 f16x8 __attribute__((ext_vector_type(8)));
typedef float    f32x4 __attribute__((ext_vector_type(4)));

#define MFMAH(a, b, c) __builtin_amdgcn_mfma_f32_16x16x32_f16(a, b, c, 0, 0, 0)

#define RING_SZ 68608            // 4 slots * 134 recs * 128 B
#define LDS_TOT (RING_SZ + 73728)

__device__ __forceinline__ unsigned short f2h(float f) {
    return __builtin_bit_cast(unsigned short, (_Float16)f);
}
__device__ __forceinline__ float h2f_bits(unsigned u) {
    return (float)__builtin_bit_cast(_Float16, (unsigned short)(u & 0xffffu));
}
__device__ __forceinline__ unsigned dup16(float g) {
    _Float16 t = (_Float16)g;
    h2 r = {t, t};
    return __builtin_bit_cast(unsigned, r);
}

__device__ __forceinline__ void blend8(const uint4* clo, const uint4* chi, uint4 gq,
                                       f16x8& bfr0, f16x8& bfr1) {
    h2 g0 = __builtin_bit_cast(h2, gq.x), g1 = __builtin_bit_cast(h2, gq.y);
    h2 g2 = __builtin_bit_cast(h2, gq.z), g3 = __builtin_bit_cast(h2, gq.w);
    const unsigned* c0 = (const unsigned*)&clo[0];
    const unsigned* c1 = (const unsigned*)&clo[1];
    const unsigned* c2 = (const unsigned*)&clo[2];
    const unsigned* c3 = (const unsigned*)&clo[3];
    const unsigned* e0 = (const unsigned*)&chi[0];
    const unsigned* e1 = (const unsigned*)&chi[1];
    const unsigned* e2 = (const unsigned*)&chi[2];
    const unsigned* e3 = (const unsigned*)&chi[3];
    unsigned owl[4], owh[4];
#pragma unroll
    for (int d = 0; d < 4; ++d) {
        h2 sl = __builtin_bit_cast(h2, c0[d]) * g0;
        sl = __builtin_elementwise_fma(__builtin_bit_cast(h2, c1[d]), g1, sl);
        sl = __builtin_elementwise_fma(__builtin_bit_cast(h2, c2[d]), g2, sl);
        sl = __builtin_elementwise_fma(__builtin_bit_cast(h2, c3[d]), g3, sl);
        owl[d] = __builtin_bit_cast(unsigned, sl);
        h2 sh = __builtin_bit_cast(h2, e0[d]) * g0;
        sh = __builtin_elementwise_fma(__builtin_bit_cast(h2, e1[d]), g1, sh);
        sh = __builtin_elementwise_fma(__builtin_bit_cast(h2, e2[d]), g2, sh);
        sh = __builtin_elementwise_fma(__builtin_bit_cast(h2, e3[d]), g3, sh);
        owh[d] = __builtin_bit_cast(unsigned, sh);
    }
    bfr0 = __builtin_bit_cast(f16x8, *(const uint4*)owl);
    bfr1 = __builtin_bit_cast(f16x8, *(const uint4*)owh);
}

// x[b][c][h][w] f32 -> xt[b][h][w][c] fp16
__global__ __launch_bounds__(256) void k_prep_xt(const float* __restrict__ x,
                                                 unsigned short* __restrict__ xt) {
    __shared__ float xs[64][129];
    const int bh = blockIdx.x;
    const int h = bh & 127, b = bh >> 7;
    const float* xr = x + ((size_t)b * 64 * 128 + h) * 128;
    for (int idx = threadIdx.x; idx < 8192; idx += 256) {
        int c = idx >> 7, w = idx & 127;
        xs[c][w] = xr[(size_t)c * 16384 + w];
    }
    __syncthreads();
    unsigned short* xto = xt + ((size_t)bh << 13);
    for (int j = threadIdx.x; j < 1024; j += 256) {
        int w = j >> 3, c0 = (j & 7) << 3;
        unsigned short tmp[8];
#pragma unroll
        for (int e = 0; e < 8; ++e) tmp[e] = f2h(xs[c0 + e][w]);
        *(uint4*)(xto + w * 64 + c0) = *(const uint4*)tmp;
    }
}

// Fragment-ordered fp16 weights (layout as R3..R9) + zero the oow flags.
__global__ void k_prep_w(const float* __restrict__ w_conv, const float* __restrict__ w_off,
                         unsigned short* __restrict__ w_m2, unsigned short* __restrict__ woff2,
                         int* __restrict__ flags) {
    int t = blockIdx.x * 256 + threadIdx.x;
    if (blockIdx.x == 0) flags[threadIdx.x] = 0;   // 256 flags
    if (t < 36864) {
        int r = t & 511;
        int fid = t >> 9;
        int l15 = r >> 5, q4 = (r >> 3) & 3, e = t & 7;
        int chunk = fid & 1, of = (fid >> 1) & 3, n = fid >> 3;
        int o = of * 16 + l15, c = chunk * 32 + q4 * 8 + e;
        w_m2[t] = f2h(w_conv[(o * 64 + c) * 9 + n]);
    }
    int t2 = t - 36864;
    if (t2 >= 0 && t2 < 18432) {
        int r = t2 & 511;
        int fid = t2 >> 9;
        int l15 = r >> 5, q4 = (r >> 3) & 3, e = t2 & 7;
        int kc = fid & 1, half = (fid >> 1) & 1, rj = fid >> 2;
        int k = half * 16 + l15, c = kc * 32 + q4 * 8 + e;
        woff2[t2] = (k < 18) ? f2h(w_off[(k * 64 + c) * 9 + rj]) : (unsigned short)0;
    }
}

// Offset conv: block = (b, h, wt-half): 64 px. Writes offg[pix][24] fp16 and
// sets flags[b*32 + h/4] if any corner row leaves the 4-row tap window.
__global__ __launch_bounds__(256) void k_off(
    const unsigned short* __restrict__ xt, const unsigned short* __restrict__ woff2,
    const float* __restrict__ b_off, _Float16* __restrict__ offg,
    int* __restrict__ flags) {
    __shared__ __align__(16) unsigned char raw3[3 * 66 * 128];

    const int gb = blockIdx.x;
    const int wt = (gb & 1) << 6, h = (gb >> 1) & 127, b = gb >> 8;

    const int tid  = threadIdx.x;
    const int lane = tid & 63, wid = tid >> 6;
    const int l15  = lane & 15, q4 = lane >> 4;
    const int lofs = ((l15 << 2) + q4) << 3;
    const int px   = wid * 16 + l15;

    const unsigned short* xtb = xt + ((size_t)b << 20);

    // stage rows h-1..h+1, cols wt-1..wt+64 (66), zero-filled, swizzled
    for (int idx = tid; idx < 1584; idx += 256) {
        int rec = idx >> 3, cc = idx & 7;
        int rl = rec / 66, col = rec - rl * 66;
        int xr = h - 1 + rl, xc = wt - 1 + col;
        uint4 v = make_uint4(0, 0, 0, 0);
        if (xr >= 0 && xr < 128 && xc >= 0 && xc < 128)
            v = *(const uint4*)(xtb + ((((size_t)xr << 7) + xc) << 6) + (cc << 3));
        *(uint4*)(raw3 + (rec << 7) + ((cc ^ (col & 7)) << 4)) = v;
    }
    __syncthreads();

    f32x4 o0 = {0.f, 0.f, 0.f, 0.f}, o1 = {0.f, 0.f, 0.f, 0.f};
#pragma unroll
    for (int rj = 0; rj < 9; ++rj) {
        const int dr = rj / 3, dj = rj % 3;
        const int colw = px + dj;
        const int recb = dr * 66 + colw;
        const int swz  = colw & 7;
#pragma unroll
        for (int kc = 0; kc < 2; ++kc) {
            f16x8 bfrag = *(const f16x8*)(raw3 + (recb << 7) + ((((kc << 2) + q4) ^ swz) << 4));
            f16x8 a0 = *(const f16x8*)((const _Float16*)woff2 + ((((rj * 2 + 0) << 1) + kc) << 9) + lofs);
            f16x8 a1 = *(const f16x8*)((const _Float16*)woff2 + ((((rj * 2 + 1) << 1) + kc) << 9) + lofs);
            o0 = MFMAH(a0, bfrag, o0);
            o1 = MFMAH(a1, bfrag, o1);
        }
    }

    float4 bo = *(const float4*)(b_off + (q4 << 2));
    float2 bo2 = *(const float2*)(b_off + 16);
    const float bov[4] = {bo.x, bo.y, bo.z, bo.w};
    const size_t pix = ((size_t)(b * 128 + h)) * 128 + wt + px;
    _Float16* og = offg + pix * 24;

    bool oow = false;
#pragma unroll
    for (int rg = 0; rg < 4; ++rg) {
        int o = (q4 << 2) + rg;
        _Float16 v16 = (_Float16)(o0[rg] + bov[rg]);
        og[o] = v16;
        if (o < 9) {   // x-offset channel -> row window check for tap n = o
            int g = o / 3;
            float pxf = (float)(h + g) + (float)v16;
            float fx = floorf(pxf);
            int qx0 = (int)fminf(fmaxf(fx, 0.f), 129.f);
            int qx1 = (int)fminf(fmaxf(fx + 1.f, 0.f), 129.f);
            int t0 = qx0 - h - g + 1, t1 = qx1 - h - g + 1;
            oow |= ((unsigned)t0 > 3u) | ((unsigned)t1 > 3u);
        }
        if (q4 == 0 && rg < 2)
            og[16 + rg] = (_Float16)(o1[rg] + (rg ? bo2.y : bo2.x));
    }
    if (__any(oow) && lane == 0) atomicOr(flags + ((b << 5) | (h >> 2)), 1);
}

// Main: persistent 4-row block (b, h4). 512 thr, 8 waves x 16 px = 128 px/row.
__global__ __launch_bounds__(512, 1) void k_fused(
    const float* __restrict__ x, const unsigned short* __restrict__ xt,
    const unsigned short* __restrict__ w_m2g, const _Float16* __restrict__ offg,
    const int* __restrict__ flags, float* __restrict__ out) {

    extern __shared__ __align__(16) unsigned char lds[];
    unsigned char* raw  = lds;                        // 4-slot row ring (134 recs/row)
    _Float16*      wlds = (_Float16*)(lds + RING_SZ); // w_m2 (36864 halves)

    const int wk = ((blockIdx.x & 7) << 5) | (blockIdx.x >> 3);   // 256 = 8 XCD x 32
    const int b = wk >> 5, h4 = wk & 31, h = h4 << 2;

    const int tid  = threadIdx.x;
    const int lane = tid & 63, wid = tid >> 6;
    const int l15  = lane & 15, q4 = lane >> 4;
    const int lofs = ((l15 << 2) + q4) << 3;
    const int px   = wid * 16 + l15;

    const unsigned short* xtb = xt + ((size_t)b << 20);
    const bool slow = (flags[(b << 5) | h4] != 0);

    // ---- stage initial ring rows (unpadded h-2..h+1) + full weight array ----
    for (int idx = tid; idx < 4288; idx += 512) {
        int rec = idx >> 3, cc = idx & 7;
        int rl = rec / 134, col = rec - rl * 134;
        int xr = h - 2 + rl, xc = col - 3;
        uint4 v = make_uint4(0, 0, 0, 0);
        if (xr >= 0 && xr < 128 && xc >= 0 && xc < 128)
            v = *(const uint4*)(xtb + ((((size_t)xr << 7) + xc) << 6) + (cc << 3));
        *(uint4*)(raw + (((xr + 4) & 3) * 134 + col << 7) + ((cc ^ (col & 7)) << 4)) = v;
    }
    for (int idx = tid; idx < 4608; idx += 512)
        ((uint4*)wlds)[idx] = ((const uint4*)w_m2g)[idx];
    __syncthreads();

    uint4 pf[3];
    int prec[3], pcc[3];
    auto PREF = [&](int u) {   // prefetch unpadded row u into regs
#pragma unroll
        for (int k = 0; k < 3; ++k) {
            int idx = tid + (k << 9);
            bool v = idx < 1072;
            int rec = idx >> 3;
            pcc[k] = idx & 7;
            int xc = rec - 3;
            uint4 vv = make_uint4(0, 0, 0, 0);
            if (v && u >= 0 && u < 128 && xc >= 0 && xc < 128)
                vv = *(const uint4*)(xtb + ((((size_t)u << 7) + xc) << 6) + (pcc[k] << 3));
            prec[k] = v ? rec : -1;
            pf[k] = vv;
        }
    };
    auto WRB = [&](int u) {    // write prefetched row u into its ring slot
        const int slt = (u + 4) & 3;
#pragma unroll
        for (int k = 0; k < 3; ++k)
            if (prec[k] >= 0)
                *(uint4*)(raw + ((slt * 134 + prec[k]) << 7) + ((pcc[k] ^ (prec[k] & 7)) << 4)) = pf[k];
    };

    if (!slow) {
        uint4 cloA[4], chiA[4], cloB[4], chiB[4];
        uint4 gqA, gqB;
        f16x8 waA[8], waB[8];

        for (int r = 0; r < 4; ++r) {
            const int R = h + r;
            const float rbF = (float)R;

            // my pixel's 18 offsets (fp16, 48B aligned)
            const _Float16* obp = offg + ((size_t)((b * 128 + R)) * 128 + px) * 24;
            uint4 oA = *(const uint4*)obp;
            uint4 oB = *(const uint4*)(obp + 8);
            unsigned oC = *(const unsigned*)(obp + 16);
            const unsigned owr[9] = {oA.x, oA.y, oA.z, oA.w, oB.x, oB.y, oB.z, oB.w, oC};
#define OXQ(n) h2f_bits(owr[(n) >> 1] >> (((n) & 1) << 4))
#define OYQ(n) h2f_bits(owr[(9 + (n)) >> 1] >> (((9 + (n)) & 1) << 4))

            // residual prefetch for this row
            const size_t obase = ((size_t)b << 20) + (size_t)R * 128 + px;
            float xres[4][4];
#pragma unroll
            for (int of = 0; of < 4; ++of)
#pragma unroll
                for (int rg = 0; rg < 4; ++rg)
                    xres[of][rg] = x[obase + (size_t)((of << 4) + (q4 << 2) + rg) * 16384];

            f32x4 acc[4];
#pragma unroll
            for (int of = 0; of < 4; ++of) acc[of] = (f32x4){0.f, 0.f, 0.f, 0.f};

#define TAPLOAD(n, S)                                                                    \
            {                                                                            \
                constexpr int g = (n) / 3, dj = (n) % 3;                                 \
                float ox = OXQ(n), oy = OYQ(n);                                          \
                float pxf = rbF + (float)g + ox, pyf = (float)(px + dj) + oy;            \
                float fx = floorf(pxf), fy = floorf(pyf);                                \
                float qx0f = fminf(fmaxf(fx, 0.f), 129.f);                               \
                float qx1f = fminf(fmaxf(fx + 1.f, 0.f), 129.f);                         \
                float qy0f = fminf(fmaxf(fy, 0.f), 129.f);                               \
                float qy1f = fminf(fmaxf(fy + 1.f, 0.f), 129.f);                         \
                float pxc = fminf(fmaxf(pxf, 0.f), 129.f);                               \
                float pyc = fminf(fmaxf(pyf, 0.f), 129.f);                               \
                float ax0 = 1.f + (qx0f - pxc), ax1 = 1.f - (qx1f - pxc);                \
                float ay0 = 1.f + (qy0f - pyc), ay1 = 1.f - (qy1f - pyc);                \
                int r0 = (((int)qx0f + 3) & 3) * 134, r1 = (((int)qx1f + 3) & 3) * 134;  \
                int c0 = (int)qy0f + 2, c1 = (int)qy1f + 2;                              \
                int blt = (r0 + c0) << 7, brb = (r1 + c1) << 7;                          \
                int blb = (r0 + c1) << 7, brt = (r1 + c0) << 7;                          \
                int z0 = ((q4 ^ c0) & 7) << 4, z1 = ((q4 ^ c1) & 7) << 4;                \
                clo##S[0] = *(const uint4*)(raw + blt + z0);                             \
                chi##S[0] = *(const uint4*)(raw + blt + (z0 ^ 64));                      \
                clo##S[1] = *(const uint4*)(raw + brb + z1);                             \
                chi##S[1] = *(const uint4*)(raw + brb + (z1 ^ 64));                      \
                clo##S[2] = *(const uint4*)(raw + blb + z1);                             \
                chi##S[2] = *(const uint4*)(raw + blb + (z1 ^ 64));                      \
                clo##S[3] = *(const uint4*)(raw + brt + z0);                             \
                chi##S[3] = *(const uint4*)(raw + brt + (z0 ^ 64));                      \
                gq##S = make_uint4(dup16(ax0 * ay0), dup16(ax1 * ay1),                   \
                                   dup16(ax0 * ay1), dup16(ax1 * ay0));                  \
                _Pragma("unroll")                                                        \
                for (int of = 0; of < 4; ++of) {                                         \
                    wa##S[2 * of]     = *(const f16x8*)(wlds + (((n) * 8 + of * 2 + 0) << 9) + lofs); \
                    wa##S[2 * of + 1] = *(const f16x8*)(wlds + (((n) * 8 + of * 2 + 1) << 9) + lofs); \
                }                                                                        \
            }
#define TAPEXEC(S)                                                                       \
            {                                                                            \
                f16x8 bfr0, bfr1;                                                        \
                blend8(clo##S, chi##S, gq##S, bfr0, bfr1);                               \
                _Pragma("unroll")                                                        \
                for (int of = 0; of < 4; ++of) {                                         \
                    acc[of] = MFMAH(wa##S[2 * of],     bfr0, acc[of]);                   \
                    acc[of] = MFMAH(wa##S[2 * of + 1], bfr1, acc[of]);                   \
                }                                                                        \
            }

            // group 0 (window padded [R-1, R+2]); prefetch padded R+3 = unpadded R+2
            PREF(R + 2);
            TAPLOAD(0, A)
            TAPLOAD(1, B) TAPEXEC(A)
            TAPLOAD(2, A) TAPEXEC(B)
                          TAPEXEC(A)
            __syncthreads(); WRB(R + 2); __syncthreads();

            // group 1 (window [R, R+3]); prefetch padded R+4 = unpadded R+3
            PREF(R + 3);
            TAPLOAD(3, A)
            TAPLOAD(4, B) TAPEXEC(A)
            TAPLOAD(5, A) TAPEXEC(B)
                          TAPEXEC(A)
            __syncthreads(); WRB(R + 3); __syncthreads();

            // group 2 (window [R+1, R+4]); prefetch stage-back padded R = unpadded R-1
            if (r < 3) PREF(R - 1);
            TAPLOAD(6, A)
            TAPLOAD(7, B) TAPEXEC(A)
            TAPLOAD(8, A) TAPEXEC(B)
                          TAPEXEC(A)
#undef TAPLOAD
#undef TAPEXEC
#undef OXQ
#undef OYQ

            // epilogue row R
#pragma unroll
            for (int of = 0; of < 4; ++of)
#pragma unroll
                for (int rg = 0; rg < 4; ++rg)
                    out[obase + (size_t)((of << 4) + (q4 << 2) + rg) * 16384] = acc[of][rg] + xres[of][rg];

            if (r < 3) { __syncthreads(); WRB(R - 1); __syncthreads(); }
        }
    } else {
        // ---- SLOW PATH (rare): all-global gather for 4 rows ----
        for (int r = 0; r < 4; ++r) {
            const int R = h + r;
            const _Float16* obp = offg + ((size_t)((b * 128 + R)) * 128 + px) * 24;
            const size_t obase = ((size_t)b << 20) + (size_t)R * 128 + px;
            f32x4 acc[4];
#pragma unroll
            for (int of = 0; of < 4; ++of) acc[of] = (f32x4){0.f, 0.f, 0.f, 0.f};
            for (int n = 0; n < 9; ++n) {
                const int g = n / 3, dj = n % 3;
                float ox = (float)obp[n], oy = (float)obp[9 + n];
                float pxf = (float)(R + g) + ox, pyf = (float)(px + dj) + oy;
                float fx = floorf(pxf), fy = floorf(pyf);
                float qx0f = fminf(fmaxf(fx, 0.f), 129.f);
                float qx1f = fminf(fmaxf(fx + 1.f, 0.f), 129.f);
                float qy0f = fminf(fmaxf(fy, 0.f), 129.f);
                float qy1f = fminf(fmaxf(fy + 1.f, 0.f), 129.f);
                float pxc = fminf(fmaxf(pxf, 0.f), 129.f);
                float pyc = fminf(fmaxf(pyf, 0.f), 129.f);
                float ax0 = 1.f + (qx0f - pxc), ax1 = 1.f - (qx1f - pxc);
                float ay0 = 1.f + (qy0f - pyc), ay1 = 1.f - (qy1f - pyc);
                int qx[2] = {(int)qx0f, (int)qx1f};
                int qy[2] = {(int)qy0f, (int)qy1f};
                uint4 clo[4], chi[4];
                const int rsel[4] = {0, 1, 0, 1}, csel[4] = {0, 1, 1, 0};
#pragma unroll
                for (int j = 0; j < 4; ++j) {
                    int rx = qx[rsel[j]], ry = qy[csel[j]];
                    bool v = (rx >= 1) & (rx <= 128) & (ry >= 1) & (ry <= 128);
                    clo[j] = make_uint4(0, 0, 0, 0);
                    chi[j] = make_uint4(0, 0, 0, 0);
                    if (v) {
                        const unsigned short* gp = xtb + ((((size_t)(rx - 1) << 7) + (ry - 1)) << 6);
                        clo[j] = *(const uint4*)(gp + (q4 << 3));
                        chi[j] = *(const uint4*)(gp + (q4 << 3) + 32);
                    }
                }
                uint4 gq = make_uint4(dup16(ax0 * ay0), dup16(ax1 * ay1),
                                      dup16(ax0 * ay1), dup16(ax1 * ay0));
                f16x8 bfr0, bfr1;
                blend8(clo, chi, gq, bfr0, bfr1);
#pragma unroll
                for (int of = 0; of < 4; ++of) {
                    f16x8 a0 = *(const f16x8*)(wlds + ((n * 8 + of * 2 + 0) << 9) + lofs);
                    f16x8 a1 = *(const f16x8*)(wlds + ((n * 8 + of * 2 + 1) << 9) + lofs);
                    acc[of] = MFMAH(a0, bfr0, acc[of]);
                    acc[of] = MFMAH(a1, bfr1, acc[of]);
                }
            }
#pragma unroll
            for (int of = 0; of < 4; ++of)
#pragma unroll
                for (int rg = 0; rg < 4; ++rg) {
                    size_t a = obase + (size_t)((of << 4) + (q4 << 2) + rg) * 16384;
                    out[a] = acc[of][rg] + x[a];
                }
        }
    }
}

extern "C" void kernel_launch(void* const* d_in, const int* in_sizes, int n_in,
                              void* d_out, int out_size, void* d_ws, size_t ws_size,
                              hipStream_t stream) {
    const float* x      = (const float*)d_in[0];
    const float* w_off  = (const float*)d_in[1];
    const float* b_off  = (const float*)d_in[2];
    const float* w_conv = (const float*)d_in[3];

    // ws layout (halves): xt 8388608 | w_m2 36864 | woff2 18432 | offg 3145728 | flags 256 ints
    unsigned short* xt    = (unsigned short*)d_ws;
    unsigned short* w_m2  = xt + (size_t)8 * 128 * 128 * 64;
    unsigned short* woff2 = w_m2 + 36864;
    _Float16*       offg  = (_Float16*)(woff2 + 18432);
    int*            flags = (int*)(offg + (size_t)131072 * 24);

    hipFuncSetAttribute((const void*)k_fused,
                        hipFuncAttributeMaxDynamicSharedMemorySize, LDS_TOT);

    hipLaunchKernelGGL(k_prep_xt, dim3(1024), dim3(256), 0, stream, x, xt);
    hipLaunchKernelGGL(k_prep_w,  dim3(216),  dim3(256), 0, stream, w_conv, w_off, w_m2, woff2, flags);
    hipLaunchKernelGGL(k_off,     dim3(2048), dim3(256), 0, stream,
                       xt, woff2, b_off, offg, flags);
    hipLaunchKernelGGL(k_fused,   dim3(256),  dim3(512), LDS_TOT, stream,
                       x, xt, w_m2, offg, flags, (float*)d_out);
}